// Round 4
// baseline (2899.190 us; speedup 1.0000x reference)
//
#include <hip/hip_runtime.h>
#include <math.h>

// ---- problem constants ----
constexpr int B_ = 32, D_ = 512, H_ = 8, L_ = 8, MLP_ = 2048, NC_ = 3;
constexpr int P_ = 256;        // patches
constexpr int N_ = 257;        // tokens (P+1)
constexpr int HD_ = 64;        // head dim
constexpr int BP_ = B_ * P_;   // 8192 patch rows
constexpr int BN_ = B_ * N_;   // 8224 token rows
constexpr int MP_ = 8320;      // BN_ padded to 65*128
constexpr int KP_ = 320;       // 5*8*8 im2col K
constexpr int NV_ = 288;       // padded n for V^T (9 k-chunks of 32)

enum { EPI_BIAS = 0, EPI_RES = 1, EPI_GELU = 2 };

using bf16x8 = __attribute__((ext_vector_type(8))) short;
using f32x4  = __attribute__((ext_vector_type(4))) float;

__device__ __forceinline__ float b2f(unsigned short u) {
    return __uint_as_float(((unsigned)u) << 16);
}
__device__ __forceinline__ unsigned short f2b(float f) {
    unsigned u = __float_as_uint(f);
    unsigned r = (u + 0x7FFFu + ((u >> 16) & 1u)) >> 16;  // RNE
    return (unsigned short)r;
}

__device__ __forceinline__ void gld_lds16(const void* g, void* l) {
    __builtin_amdgcn_global_load_lds(
        (const __attribute__((address_space(1))) void*)g,
        (__attribute__((address_space(3))) void*)l, 16, 0, 0);
}

// ---------------- im2col (bf16 out) ----------------
__global__ void im2col_k(const float* __restrict__ img,
                         unsigned short* __restrict__ X) {
    int idx = blockIdx.x * 256 + threadIdx.x;
    if (idx >= BP_ * KP_) return;
    int r = idx / KP_, j = idx % KP_;
    int b = r >> 8, p = r & 255;
    int py = p >> 4, px = p & 15;
    int c = j >> 6, kk = j & 63;
    int ky = kk >> 3, kx = kk & 7;
    const int dy[5] = {0, 1, -1, 1, -1};
    const int dx[5] = {0, 1, 1, -1, -1};
    int yy = (py * 8 + ky - dy[c] + 128) & 127;
    int xx = (px * 8 + kx - dx[c] + 128) & 127;
    X[idx] = f2b(img[b * 16384 + yy * 128 + xx]);
}

// ---------------- transpose + cast fp32 KxN -> bf16 NxK ----------------
__global__ __launch_bounds__(256) void castT_k(const float* __restrict__ in,
                                               unsigned short* __restrict__ out,
                                               int K, int N) {
    __shared__ float t[32][33];
    size_t loff = (size_t)blockIdx.z * K * N;
    int k0 = blockIdx.x * 32, n0 = blockIdx.y * 32;
    int tx = threadIdx.x & 31, ty = threadIdx.x >> 5;
    for (int i = ty; i < 32; i += 8)
        t[i][tx] = in[loff + (size_t)(k0 + i) * N + n0 + tx];
    __syncthreads();
    for (int i = ty; i < 32; i += 8)
        out[loff + (size_t)(n0 + i) * K + k0 + tx] = f2b(t[tx][i]);
}

// ---------------- plain cast ----------------
__global__ void cast_k(const float* __restrict__ in,
                       unsigned short* __restrict__ out, int n) {
    int idx = blockIdx.x * 256 + threadIdx.x;
    if (idx < n) out[idx] = f2b(in[idx]);
}

// ---------------- bf16 MFMA GEMM: C[M,N] = A[M,K] @ Bt[N,K]^T ----------------
__global__ __launch_bounds__(256) void gemm_bf16_k(
    const unsigned short* __restrict__ A, const unsigned short* __restrict__ Bt,
    const float* __restrict__ bias, const float* __restrict__ res,
    float* __restrict__ outF, unsigned short* __restrict__ outB,
    int Nn, int K, int epi) {
    constexpr int BK = 32;
    __shared__ unsigned short As[128 * BK];
    __shared__ unsigned short Bs[128 * BK];
    int tid = threadIdx.x, lane = tid & 63;
    int wave = tid >> 6;
    int wrow = (wave >> 1) * 64, wcol = (wave & 1) * 64;
    size_t bm = (size_t)blockIdx.y * 128, bn = (size_t)blockIdx.x * 128;
    const unsigned short* Ab = A + bm * K;
    const unsigned short* Bb = Bt + bn * K;

    f32x4 acc[4][4] = {};
    int quad = lane >> 4, col = lane & 15;
    int q8 = quad * 8;

    for (int k0 = 0; k0 < K; k0 += BK) {
#pragma unroll
        for (int it = 0; it < 2; ++it) {
            int c = it * 256 + tid;
            int row = c >> 2, cb = (c & 3) * 8;
            gld_lds16(Ab + (size_t)row * K + k0 + cb, (char*)As + c * 16);
            gld_lds16(Bb + (size_t)row * K + k0 + cb, (char*)Bs + c * 16);
        }
        __syncthreads();
        bf16x8 af[4], bfr[4];
#pragma unroll
        for (int i = 0; i < 4; ++i) {
            af[i]  = *(const bf16x8*)&As[(wrow + i * 16 + col) * BK + q8];
            bfr[i] = *(const bf16x8*)&Bs[(wcol + i * 16 + col) * BK + q8];
        }
#pragma unroll
        for (int mi = 0; mi < 4; ++mi)
#pragma unroll
            for (int ni = 0; ni < 4; ++ni)
                acc[mi][ni] = __builtin_amdgcn_mfma_f32_16x16x32_bf16(
                    af[mi], bfr[ni], acc[mi][ni], 0, 0, 0);
        __syncthreads();
    }

#pragma unroll
    for (int mi = 0; mi < 4; ++mi) {
#pragma unroll
        for (int ni = 0; ni < 4; ++ni) {
            size_t gm0 = bm + wrow + mi * 16 + quad * 4;
            size_t gn = bn + wcol + ni * 16 + col;
            float bs = bias ? bias[gn] : 0.f;
#pragma unroll
            for (int r = 0; r < 4; ++r) {
                size_t o = (gm0 + r) * Nn + gn;
                float v = acc[mi][ni][r] + bs;
                if (epi == EPI_GELU)
                    v = 0.5f * v * (1.f + erff(v * 0.70710678118654752f));
                else if (epi == EPI_RES)
                    v += res[o];
                if (outF) outF[o] = v;
                if (outB) outB[o] = f2b(v);
            }
        }
    }
}

// ---------------- LayerNorm D=512, dual output ----------------
__global__ __launch_bounds__(256) void ln_k(
    const float* __restrict__ in, float* __restrict__ outF,
    unsigned short* __restrict__ outB, const float* __restrict__ g,
    const float* __restrict__ be, long instride, long ofs, long obs) {
    __shared__ float red[256];
    int row = blockIdx.x;
    const float* x = in + (size_t)row * instride;
    int t = threadIdx.x;
    float v0 = x[t], v1 = x[t + 256];
    red[t] = v0 + v1;
    __syncthreads();
    for (int s = 128; s > 0; s >>= 1) {
        if (t < s) red[t] += red[t + s];
        __syncthreads();
    }
    float mu = red[0] * (1.f / 512.f);
    __syncthreads();
    float d0 = v0 - mu, d1 = v1 - mu;
    red[t] = d0 * d0 + d1 * d1;
    __syncthreads();
    for (int s = 128; s > 0; s >>= 1) {
        if (t < s) red[t] += red[t + s];
        __syncthreads();
    }
    float rs = rsqrtf(red[0] * (1.f / 512.f) + 1e-5f);
    float y0 = d0 * rs * g[t] + be[t];
    float y1 = d1 * rs * g[t + 256] + be[t + 256];
    if (outF) {
        float* y = outF + (size_t)row * ofs;
        y[t] = y0; y[t + 256] = y1;
    }
    if (outB) {
        unsigned short* y = outB + (size_t)row * obs;
        y[t] = f2b(y0); y[t + 256] = f2b(y1);
    }
}

// ------- gate sigmoid + fuse + cls + pos_embed -> tokens (fp32) -------
__global__ void assemble_k(const float* __restrict__ gatelin,
                           const float* __restrict__ src,
                           const float* __restrict__ orig,
                           const float* __restrict__ cls,
                           const float* __restrict__ pos,
                           float* __restrict__ tokens) {
    int idx = blockIdx.x * 256 + threadIdx.x;
    if (idx >= B_ * N_ * D_) return;
    int d = idx & 511;
    int bn = idx >> 9;
    int b = bn / N_, n = bn % N_;
    float v;
    if (n == 0) {
        v = cls[d];
    } else {
        int r = b * 256 + (n - 1);
        float gl = gatelin[r * 512 + d];
        float g = 1.f / (1.f + expf(-gl));
        v = g * src[r * 512 + d] + (1.f - g) * orig[r * 512 + d];
    }
    tokens[idx] = v + pos[n * 512 + d];
}

// ---------------- V transpose: qkv -> Vt_g[bh][64][NV_] ----------------
// grid: (bh=256, nt=5), 256 threads. nt covers n0 = nt*64 .. +63.
__global__ __launch_bounds__(256) void vT_k(const unsigned short* __restrict__ qkv,
                                            unsigned short* __restrict__ Vt_g) {
    __shared__ unsigned short t[64][72];
    int bh = blockIdx.x, nt = blockIdx.y;
    int b = bh >> 3, h = bh & 7;
    int n0 = nt * 64;
    const unsigned short* vb = qkv + (size_t)(b * N_) * 1536 + 1024 + h * 64;
    int tid = threadIdx.x;
    for (int idx = tid; idx < 64 * 8; idx += 256) {
        int n = idx >> 3, c = idx & 7;
        int gn = n0 + n;
        uint4 u = {0, 0, 0, 0};
        if (gn < N_) u = *(const uint4*)(vb + (size_t)gn * 1536 + c * 8);
        *(uint4*)&t[n][c * 8] = u;
    }
    __syncthreads();
    for (int idx = tid; idx < 64 * 8; idx += 256) {
        int d = idx >> 3, j = idx & 7;
        if (n0 + j * 8 >= NV_) continue;
        unsigned short tmp[8];
#pragma unroll
        for (int e = 0; e < 8; ++e) tmp[e] = t[j * 8 + e][d];
        *(uint4*)&Vt_g[((size_t)bh * 64 + d) * NV_ + n0 + j * 8] =
            *(uint4*)tmp;
    }
}

// ---------------- fused flash attention v2: one wave per q-tile ----------------
// grid: (bh=256, qg=5), 256 threads = 4 waves; wave handles q-tile qg*4+wave.
__global__ __launch_bounds__(256) void attn_fused_k(
    const unsigned short* __restrict__ qkv,
    const unsigned short* __restrict__ Vt_g, const float* __restrict__ temp,
    unsigned short* __restrict__ obuf) {
    __shared__ __align__(16) unsigned short Ps[4][16][40];
    int bh = blockIdx.x;
    int b = bh >> 3, h = bh & 7;
    int tid = threadIdx.x, lane = tid & 63, wave = tid >> 6;
    int quad = lane >> 4, cid = lane & 15;
    int qt = blockIdx.y * 4 + wave;
    if (qt > 16) return;
    const unsigned short* qb = qkv + (size_t)(b * N_) * 1536 + h * 64;
    const unsigned short* kb = qb + 512;
    const unsigned short* vt = Vt_g + (size_t)bh * 64 * NV_;
    float tmp = temp[h];

    int qrow = qt * 16 + cid;
    if (qrow > 256) qrow = 256;
    bf16x8 aq0 = *(const bf16x8*)(qb + (size_t)qrow * 1536 + quad * 8);
    bf16x8 aq1 = *(const bf16x8*)(qb + (size_t)qrow * 1536 + 32 + quad * 8);

    f32x4 s[18];
#pragma unroll 4
    for (int t = 0; t < 16; ++t) {  // krow = t*16+cid <= 255, no clamp
        const unsigned short* kp = kb + (size_t)(t * 16 + cid) * 1536 + quad * 8;
        bf16x8 bk0 = *(const bf16x8*)kp;
        bf16x8 bk1 = *(const bf16x8*)(kp + 32);
        f32x4 a = {0.f, 0.f, 0.f, 0.f};
        a = __builtin_amdgcn_mfma_f32_16x16x32_bf16(aq0, bk0, a, 0, 0, 0);
        a = __builtin_amdgcn_mfma_f32_16x16x32_bf16(aq1, bk1, a, 0, 0, 0);
        s[t] = a;
    }
    {   // t = 16 tail, krow clamped
        int krow = 256 + cid;
        if (krow > 256) krow = 256;
        const unsigned short* kp = kb + (size_t)krow * 1536 + quad * 8;
        bf16x8 bk0 = *(const bf16x8*)kp;
        bf16x8 bk1 = *(const bf16x8*)(kp + 32);
        f32x4 a = {0.f, 0.f, 0.f, 0.f};
        a = __builtin_amdgcn_mfma_f32_16x16x32_bf16(aq0, bk0, a, 0, 0, 0);
        a = __builtin_amdgcn_mfma_f32_16x16x32_bf16(aq1, bk1, a, 0, 0, 0);
        s[16] = a;
    }

    // mask + row max (rows = qt*16 + quad*4 + r, cols = t*16 + cid)
    float mx[4] = {-1e30f, -1e30f, -1e30f, -1e30f};
#pragma unroll
    for (int t = 0; t < 17; ++t) {
        int col = t * 16 + cid;
#pragma unroll
        for (int r = 0; r < 4; ++r) {
            int row = qt * 16 + quad * 4 + r;
            float v = s[t][r] * tmp;
            if (col == row || col >= 257) v = -1e30f;
            s[t][r] = v;
            mx[r] = fmaxf(mx[r], v);
        }
    }
    s[17] = f32x4{-1e30f, -1e30f, -1e30f, -1e30f};
#pragma unroll
    for (int m = 1; m < 16; m <<= 1)
#pragma unroll
        for (int r = 0; r < 4; ++r) mx[r] = fmaxf(mx[r], __shfl_xor(mx[r], m));
    float sum[4] = {0.f, 0.f, 0.f, 0.f};
#pragma unroll
    for (int t = 0; t < 18; ++t)
#pragma unroll
        for (int r = 0; r < 4; ++r) {
            float e = __expf(s[t][r] - mx[r]);
            float ef = b2f(f2b(e));
            s[t][r] = ef;
            sum[r] += ef;
        }
#pragma unroll
    for (int m = 1; m < 16; m <<= 1)
#pragma unroll
        for (int r = 0; r < 4; ++r) sum[r] += __shfl_xor(sum[r], m);
    float inv[4];
#pragma unroll
    for (int r = 0; r < 4; ++r) inv[r] = 1.f / sum[r];

    // PV: 9 k-chunks of 32 over n
    f32x4 o[4] = {};
#pragma unroll 3
    for (int kt = 0; kt < 9; ++kt) {
#pragma unroll
        for (int hh = 0; hh < 2; ++hh) {
            int t = kt * 2 + hh;
#pragma unroll
            for (int r = 0; r < 4; ++r)
                Ps[wave][quad * 4 + r][hh * 16 + cid] = f2b(s[t][r]);
        }
        bf16x8 ap = *(const bf16x8*)&Ps[wave][cid][quad * 8];
#pragma unroll
        for (int dt = 0; dt < 4; ++dt) {
            bf16x8 bv = *(const bf16x8*)(vt + (size_t)(dt * 16 + cid) * NV_ +
                                         kt * 32 + quad * 8);
            o[dt] =
                __builtin_amdgcn_mfma_f32_16x16x32_bf16(ap, bv, o[dt], 0, 0, 0);
        }
    }
#pragma unroll
    for (int dt = 0; dt < 4; ++dt)
#pragma unroll
        for (int r = 0; r < 4; ++r) {
            int row = qt * 16 + quad * 4 + r;
            if (row < N_)
                obuf[(size_t)(b * N_ + row) * 512 + h * 64 + dt * 16 + cid] =
                    f2b(o[dt][r] * inv[r]);
        }
}

// ------- head (fp32, tiny) -------
__global__ void head_k(const float* __restrict__ cls_out,
                       const float* __restrict__ hw,
                       const float* __restrict__ hb, float* __restrict__ out) {
    int t = threadIdx.x;
    if (t >= B_ * NC_) return;
    int b = t / NC_, c = t % NC_;
    float acc = hb[c];
    for (int d = 0; d < D_; ++d) acc += cls_out[b * D_ + d] * hw[d * NC_ + c];
    out[t] = acc;
}

extern "C" void kernel_launch(void* const* d_in, const int* in_sizes, int n_in,
                              void* d_out, int out_size, void* d_ws,
                              size_t ws_size, hipStream_t stream) {
    const float* image     = (const float*)d_in[0];
    const float* ssw       = (const float*)d_in[1];
    const float* ssb       = (const float*)d_in[2];
    const float* ssg       = (const float*)d_in[3];
    const float* ssbeta    = (const float*)d_in[4];
    const float* sow       = (const float*)d_in[5];
    const float* sob       = (const float*)d_in[6];
    const float* sog       = (const float*)d_in[7];
    const float* sobeta    = (const float*)d_in[8];
    const float* fw        = (const float*)d_in[9];
    const float* fb        = (const float*)d_in[10];
    const float* cls_token = (const float*)d_in[11];
    const float* pos_embed = (const float*)d_in[12];
    const float* ln1g      = (const float*)d_in[13];
    const float* ln1b      = (const float*)d_in[14];
    const float* qkvw      = (const float*)d_in[15];
    const float* qkvb      = (const float*)d_in[16];
    const float* projw     = (const float*)d_in[17];
    const float* projb     = (const float*)d_in[18];
    const float* temp      = (const float*)d_in[19];
    const float* ln2g      = (const float*)d_in[20];
    const float* ln2b      = (const float*)d_in[21];
    const float* w1        = (const float*)d_in[22];
    const float* b1        = (const float*)d_in[23];
    const float* w2        = (const float*)d_in[24];
    const float* b2        = (const float*)d_in[25];
    const float* ng        = (const float*)d_in[26];
    const float* nb        = (const float*)d_in[27];
    const float* hw        = (const float*)d_in[28];
    const float* hb        = (const float*)d_in[29];
    float* out = (float*)d_out;

    char* w = (char*)d_ws;
    size_t off = 0;
    float* tokens = (float*)w;                           off += (size_t)MP_ * 512 * 4;
    unsigned short* qkvw_t = (unsigned short*)(w + off); off += (size_t)8 * 1536 * 512 * 2;
    unsigned short* projw_t = (unsigned short*)(w + off); off += (size_t)8 * 512 * 512 * 2;
    unsigned short* w1_t = (unsigned short*)(w + off);   off += (size_t)8 * 2048 * 512 * 2;
    unsigned short* w2_t = (unsigned short*)(w + off);   off += (size_t)8 * 512 * 2048 * 2;
    unsigned short* fw_t = (unsigned short*)(w + off);   off += (size_t)512 * 1024 * 2;
    unsigned short* sswb = (unsigned short*)(w + off);   off += (size_t)512 * 320 * 2;
    unsigned short* sowb = (unsigned short*)(w + off);   off += (size_t)512 * 320 * 2;
    char* S = w + off;

    // prestage aliases (dead after assemble_k)
    unsigned short* Xb   = (unsigned short*)S;
    float* srct          = (float*)(S + 5242880);
    float* origt         = (float*)(S + 5242880 + 16777216);
    unsigned short* comb = (unsigned short*)(S + 5242880 + 2 * 16777216);
    float* gatelin       = (float*)(S + 5242880 + 3 * 16777216);

    // per-layer aliases
    unsigned short* xbuf = (unsigned short*)S;                      // 8,519,680
    unsigned short* qkvB = (unsigned short*)(S + 8519680);          // 25,559,040
    unsigned short* obuf = (unsigned short*)(S + 8519680 + 25559040);            // 8,519,680
    unsigned short* hbuf = (unsigned short*)(S + 8519680 + 25559040 + 8519680);  // 34,078,720
    unsigned short* vt_g = (unsigned short*)(S + 8519680 + 25559040 + 8519680 +
                                             34078720);             // 9,437,184
    float* cls_out = (float*)(S + 8519680 + 25559040 + 8519680 + 34078720 +
                              9437184);

    // ---- weight casts/transposes (bf16, N x K) ----
    castT_k<<<dim3(16, 48, 8), 256, 0, stream>>>(qkvw, qkvw_t, 512, 1536);
    castT_k<<<dim3(16, 16, 8), 256, 0, stream>>>(projw, projw_t, 512, 512);
    castT_k<<<dim3(16, 64, 8), 256, 0, stream>>>(w1, w1_t, 512, 2048);
    castT_k<<<dim3(64, 16, 8), 256, 0, stream>>>(w2, w2_t, 2048, 512);
    castT_k<<<dim3(32, 16, 1), 256, 0, stream>>>(fw, fw_t, 1024, 512);
    cast_k<<<640, 256, 0, stream>>>(ssw, sswb, 512 * 320);
    cast_k<<<640, 256, 0, stream>>>(sow, sowb, 512 * 320);

    // ---- SPT ----
    im2col_k<<<(BP_ * KP_ + 255) / 256, 256, 0, stream>>>(image, Xb);
    dim3 gspt(4, 64);
    gemm_bf16_k<<<gspt, 256, 0, stream>>>(Xb, sswb, ssb, nullptr, srct, nullptr,
                                          512, KP_, EPI_BIAS);
    ln_k<<<BP_, 256, 0, stream>>>(srct, srct, comb, ssg, ssbeta, 512, 512, 1024);
    gemm_bf16_k<<<gspt, 256, 0, stream>>>(Xb, sowb, sob, nullptr, origt, nullptr,
                                          512, KP_, EPI_BIAS);
    ln_k<<<BP_, 256, 0, stream>>>(origt, origt, comb + 512, sog, sobeta, 512,
                                  512, 1024);
    // ---- gated fusion ----
    gemm_bf16_k<<<gspt, 256, 0, stream>>>(comb, fw_t, fb, nullptr, gatelin,
                                          nullptr, 512, 1024, EPI_BIAS);
    assemble_k<<<(B_ * N_ * D_ + 255) / 256, 256, 0, stream>>>(
        gatelin, srct, origt, cls_token, pos_embed, tokens);

    // ---- transformer layers ----
    dim3 gqkv(12, 65), gproj(4, 65), gfc1(16, 65);
    for (int l = 0; l < L_; ++l) {
        const float* l1g = ln1g + l * D_;
        const float* l1b = ln1b + l * D_;
        const unsigned short* qw = qkvw_t + (size_t)l * 1536 * 512;
        const float* qb  = qkvb + (size_t)l * 3 * D_;
        const unsigned short* pw = projw_t + (size_t)l * 512 * 512;
        const float* pb  = projb + (size_t)l * D_;
        const float* tp  = temp + l * H_;
        const float* l2g = ln2g + l * D_;
        const float* l2b = ln2b + l * D_;
        const unsigned short* w1l = w1_t + (size_t)l * 2048 * 512;
        const float* b1l = b1 + (size_t)l * MLP_;
        const unsigned short* w2l = w2_t + (size_t)l * 512 * 2048;
        const float* b2l = b2 + (size_t)l * D_;

        ln_k<<<BN_, 256, 0, stream>>>(tokens, nullptr, xbuf, l1g, l1b, 512, 0,
                                      512);
        gemm_bf16_k<<<gqkv, 256, 0, stream>>>(xbuf, qw, qb, nullptr, nullptr,
                                              qkvB, 1536, 512, EPI_BIAS);
        vT_k<<<dim3(256, 5), 256, 0, stream>>>(qkvB, vt_g);
        attn_fused_k<<<dim3(256, 5), 256, 0, stream>>>(qkvB, vt_g, tp, obuf);
        gemm_bf16_k<<<gproj, 256, 0, stream>>>(obuf, pw, pb, tokens, tokens,
                                               nullptr, 512, 512, EPI_RES);
        ln_k<<<BN_, 256, 0, stream>>>(tokens, nullptr, xbuf, l2g, l2b, 512, 0,
                                      512);
        gemm_bf16_k<<<gfc1, 256, 0, stream>>>(xbuf, w1l, b1l, nullptr, nullptr,
                                              hbuf, 2048, 512, EPI_GELU);
        gemm_bf16_k<<<gproj, 256, 0, stream>>>(hbuf, w2l, b2l, tokens, tokens,
                                               nullptr, 512, 2048, EPI_RES);
    }

    // ---- final LN on cls token + head ----
    ln_k<<<B_, 256, 0, stream>>>(tokens, cls_out, nullptr, ng, nb,
                                 (long)N_ * 512, 512, 0);
    head_k<<<1, 128, 0, stream>>>(cls_out, hw, hb, out);
}

// Round 5
// 2523.945 us; speedup vs baseline: 1.1487x; 1.1487x over previous
//
#include <hip/hip_runtime.h>
#include <math.h>

// ---- problem constants ----
constexpr int B_ = 32, D_ = 512, H_ = 8, L_ = 8, MLP_ = 2048, NC_ = 3;
constexpr int P_ = 256;        // patches
constexpr int N_ = 257;        // tokens (P+1)
constexpr int HD_ = 64;        // head dim
constexpr int BP_ = B_ * P_;   // 8192 patch rows
constexpr int BN_ = B_ * N_;   // 8224 token rows
constexpr int MP_ = 8320;      // BN_ padded to 65*128
constexpr int KP_ = 320;       // 5*8*8 im2col K
constexpr int NV_ = 288;       // padded n for V^T (9 k-chunks of 32)

enum { EPI_BIAS = 0, EPI_RES = 1, EPI_GELU = 2 };

using bf16x8 = __attribute__((ext_vector_type(8))) short;
using f32x4  = __attribute__((ext_vector_type(4))) float;

__device__ __forceinline__ float b2f(unsigned short u) {
    return __uint_as_float(((unsigned)u) << 16);
}
__device__ __forceinline__ unsigned short f2b(float f) {
    unsigned u = __float_as_uint(f);
    unsigned r = (u + 0x7FFFu + ((u >> 16) & 1u)) >> 16;  // RNE
    return (unsigned short)r;
}

__device__ __forceinline__ void gld_lds16(const void* g, void* l) {
    __builtin_amdgcn_global_load_lds(
        (const __attribute__((address_space(1))) void*)g,
        (__attribute__((address_space(3))) void*)l, 16, 0, 0);
}

// ---------------- im2col (bf16 out) ----------------
__global__ void im2col_k(const float* __restrict__ img,
                         unsigned short* __restrict__ X) {
    int idx = blockIdx.x * 256 + threadIdx.x;
    if (idx >= BP_ * KP_) return;
    int r = idx / KP_, j = idx % KP_;
    int b = r >> 8, p = r & 255;
    int py = p >> 4, px = p & 15;
    int c = j >> 6, kk = j & 63;
    int ky = kk >> 3, kx = kk & 7;
    const int dy[5] = {0, 1, -1, 1, -1};
    const int dx[5] = {0, 1, 1, -1, -1};
    int yy = (py * 8 + ky - dy[c] + 128) & 127;
    int xx = (px * 8 + kx - dx[c] + 128) & 127;
    X[idx] = f2b(img[b * 16384 + yy * 128 + xx]);
}

// ---------------- transpose + cast fp32 KxN -> bf16 NxK ----------------
__global__ __launch_bounds__(256) void castT_k(const float* __restrict__ in,
                                               unsigned short* __restrict__ out,
                                               int K, int N) {
    __shared__ float t[32][33];
    size_t loff = (size_t)blockIdx.z * K * N;
    int k0 = blockIdx.x * 32, n0 = blockIdx.y * 32;
    int tx = threadIdx.x & 31, ty = threadIdx.x >> 5;
    for (int i = ty; i < 32; i += 8)
        t[i][tx] = in[loff + (size_t)(k0 + i) * N + n0 + tx];
    __syncthreads();
    for (int i = ty; i < 32; i += 8)
        out[loff + (size_t)(n0 + i) * K + k0 + tx] = f2b(t[tx][i]);
}

// ---------------- plain cast ----------------
__global__ void cast_k(const float* __restrict__ in,
                       unsigned short* __restrict__ out, int n) {
    int idx = blockIdx.x * 256 + threadIdx.x;
    if (idx < n) out[idx] = f2b(in[idx]);
}

// ---------------- bf16 MFMA GEMM: C[M,N] = A[M,K] @ Bt[N,K]^T ----------------
__global__ __launch_bounds__(256) void gemm_bf16_k(
    const unsigned short* __restrict__ A, const unsigned short* __restrict__ Bt,
    const float* __restrict__ bias, const float* __restrict__ res,
    float* __restrict__ outF, unsigned short* __restrict__ outB,
    int Nn, int K, int epi) {
    constexpr int BK = 32;
    __shared__ unsigned short As[128 * BK];
    __shared__ unsigned short Bs[128 * BK];
    int tid = threadIdx.x, lane = tid & 63;
    int wave = tid >> 6;
    int wrow = (wave >> 1) * 64, wcol = (wave & 1) * 64;
    size_t bm = (size_t)blockIdx.y * 128, bn = (size_t)blockIdx.x * 128;
    const unsigned short* Ab = A + bm * K;
    const unsigned short* Bb = Bt + bn * K;

    f32x4 acc[4][4] = {};
    int quad = lane >> 4, col = lane & 15;
    int q8 = quad * 8;

    for (int k0 = 0; k0 < K; k0 += BK) {
#pragma unroll
        for (int it = 0; it < 2; ++it) {
            int c = it * 256 + tid;
            int row = c >> 2, cb = (c & 3) * 8;
            gld_lds16(Ab + (size_t)row * K + k0 + cb, (char*)As + c * 16);
            gld_lds16(Bb + (size_t)row * K + k0 + cb, (char*)Bs + c * 16);
        }
        __syncthreads();
        bf16x8 af[4], bfr[4];
#pragma unroll
        for (int i = 0; i < 4; ++i) {
            af[i]  = *(const bf16x8*)&As[(wrow + i * 16 + col) * BK + q8];
            bfr[i] = *(const bf16x8*)&Bs[(wcol + i * 16 + col) * BK + q8];
        }
#pragma unroll
        for (int mi = 0; mi < 4; ++mi)
#pragma unroll
            for (int ni = 0; ni < 4; ++ni)
                acc[mi][ni] = __builtin_amdgcn_mfma_f32_16x16x32_bf16(
                    af[mi], bfr[ni], acc[mi][ni], 0, 0, 0);
        __syncthreads();
    }

#pragma unroll
    for (int mi = 0; mi < 4; ++mi) {
#pragma unroll
        for (int ni = 0; ni < 4; ++ni) {
            size_t gm0 = bm + wrow + mi * 16 + quad * 4;
            size_t gn = bn + wcol + ni * 16 + col;
            float bs = bias ? bias[gn] : 0.f;
#pragma unroll
            for (int r = 0; r < 4; ++r) {
                size_t o = (gm0 + r) * Nn + gn;
                float v = acc[mi][ni][r] + bs;
                if (epi == EPI_GELU)
                    v = 0.5f * v * (1.f + erff(v * 0.70710678118654752f));
                else if (epi == EPI_RES)
                    v += res[o];
                if (outF) outF[o] = v;
                if (outB) outB[o] = f2b(v);
            }
        }
    }
}

// ---------------- LayerNorm D=512, dual output ----------------
__global__ __launch_bounds__(256) void ln_k(
    const float* __restrict__ in, float* __restrict__ outF,
    unsigned short* __restrict__ outB, const float* __restrict__ g,
    const float* __restrict__ be, long instride, long ofs, long obs) {
    __shared__ float red[256];
    int row = blockIdx.x;
    const float* x = in + (size_t)row * instride;
    int t = threadIdx.x;
    float v0 = x[t], v1 = x[t + 256];
    red[t] = v0 + v1;
    __syncthreads();
    for (int s = 128; s > 0; s >>= 1) {
        if (t < s) red[t] += red[t + s];
        __syncthreads();
    }
    float mu = red[0] * (1.f / 512.f);
    __syncthreads();
    float d0 = v0 - mu, d1 = v1 - mu;
    red[t] = d0 * d0 + d1 * d1;
    __syncthreads();
    for (int s = 128; s > 0; s >>= 1) {
        if (t < s) red[t] += red[t + s];
        __syncthreads();
    }
    float rs = rsqrtf(red[0] * (1.f / 512.f) + 1e-5f);
    float y0 = d0 * rs * g[t] + be[t];
    float y1 = d1 * rs * g[t + 256] + be[t + 256];
    if (outF) {
        float* y = outF + (size_t)row * ofs;
        y[t] = y0; y[t + 256] = y1;
    }
    if (outB) {
        unsigned short* y = outB + (size_t)row * obs;
        y[t] = f2b(y0); y[t + 256] = f2b(y1);
    }
}

// ------- gate sigmoid + fuse + cls + pos_embed -> tokens (fp32) -------
__global__ void assemble_k(const float* __restrict__ gatelin,
                           const float* __restrict__ src,
                           const float* __restrict__ orig,
                           const float* __restrict__ cls,
                           const float* __restrict__ pos,
                           float* __restrict__ tokens) {
    int idx = blockIdx.x * 256 + threadIdx.x;
    if (idx >= B_ * N_ * D_) return;
    int d = idx & 511;
    int bn = idx >> 9;
    int b = bn / N_, n = bn % N_;
    float v;
    if (n == 0) {
        v = cls[d];
    } else {
        int r = b * 256 + (n - 1);
        float gl = gatelin[r * 512 + d];
        float g = 1.f / (1.f + expf(-gl));
        v = g * src[r * 512 + d] + (1.f - g) * orig[r * 512 + d];
    }
    tokens[idx] = v + pos[n * 512 + d];
}

// ---------------- V transpose: qkv -> Vt_g[bh][64][NV_] ----------------
__global__ __launch_bounds__(256) void vT_k(const unsigned short* __restrict__ qkv,
                                            unsigned short* __restrict__ Vt_g) {
    __shared__ unsigned short t[64][72];
    int bh = blockIdx.x, nt = blockIdx.y;
    int b = bh >> 3, h = bh & 7;
    int n0 = nt * 64;
    const unsigned short* vb = qkv + (size_t)(b * N_) * 1536 + 1024 + h * 64;
    int tid = threadIdx.x;
    for (int idx = tid; idx < 64 * 8; idx += 256) {
        int n = idx >> 3, c = idx & 7;
        int gn = n0 + n;
        uint4 u = {0, 0, 0, 0};
        if (gn < N_) u = *(const uint4*)(vb + (size_t)gn * 1536 + c * 8);
        *(uint4*)&t[n][c * 8] = u;
    }
    __syncthreads();
    for (int idx = tid; idx < 64 * 8; idx += 256) {
        int d = idx >> 3, j = idx & 7;
        if (n0 + j * 8 >= NV_) continue;
        unsigned short tmp[8];
#pragma unroll
        for (int e = 0; e < 8; ++e) tmp[e] = t[j * 8 + e][d];
        *(uint4*)&Vt_g[((size_t)bh * 64 + d) * NV_ + n0 + j * 8] =
            *(uint4*)tmp;
    }
}

// ---------------- fused flash attention v3: one wave per q-tile --------------
// grid: (bh=256, qg=5), 256 threads = 4 waves. FULLY UNROLLED so the score
// array s[18] stays in VGPRs — partial unroll forced it to scratch (round 4:
// 220 MB/dispatch spill writes, the real bottleneck).
__global__ __launch_bounds__(256) void attn_fused_k(
    const unsigned short* __restrict__ qkv,
    const unsigned short* __restrict__ Vt_g, const float* __restrict__ temp,
    unsigned short* __restrict__ obuf) {
    __shared__ __align__(16) unsigned short Ps[4][16][40];
    int bh = blockIdx.x;
    int b = bh >> 3, h = bh & 7;
    int tid = threadIdx.x, lane = tid & 63, wave = tid >> 6;
    int quad = lane >> 4, cid = lane & 15;
    int qt = blockIdx.y * 4 + wave;
    if (qt > 16) return;
    const unsigned short* qb = qkv + (size_t)(b * N_) * 1536 + h * 64;
    const unsigned short* kb = qb + 512;
    const unsigned short* vt = Vt_g + (size_t)bh * 64 * NV_;
    float tmp = temp[h];

    int qrow = qt * 16 + cid;
    if (qrow > 256) qrow = 256;
    bf16x8 aq0 = *(const bf16x8*)(qb + (size_t)qrow * 1536 + quad * 8);
    bf16x8 aq1 = *(const bf16x8*)(qb + (size_t)qrow * 1536 + 32 + quad * 8);

    f32x4 s[18];
#pragma unroll
    for (int t = 0; t < 17; ++t) {
        int krow = t * 16 + cid;
        if (t == 16 && krow > 256) krow = 256;  // static after full unroll
        const unsigned short* kp = kb + (size_t)krow * 1536 + quad * 8;
        bf16x8 bk0 = *(const bf16x8*)kp;
        bf16x8 bk1 = *(const bf16x8*)(kp + 32);
        f32x4 a = {0.f, 0.f, 0.f, 0.f};
        a = __builtin_amdgcn_mfma_f32_16x16x32_bf16(aq0, bk0, a, 0, 0, 0);
        a = __builtin_amdgcn_mfma_f32_16x16x32_bf16(aq1, bk1, a, 0, 0, 0);
        s[t] = a;
    }

    // mask + row max (rows = qt*16 + quad*4 + r, cols = t*16 + cid)
    float mx[4] = {-1e30f, -1e30f, -1e30f, -1e30f};
#pragma unroll
    for (int t = 0; t < 17; ++t) {
        int col = t * 16 + cid;
#pragma unroll
        for (int r = 0; r < 4; ++r) {
            int row = qt * 16 + quad * 4 + r;
            float v = s[t][r] * tmp;
            if (col == row || col >= 257) v = -1e30f;
            s[t][r] = v;
            mx[r] = fmaxf(mx[r], v);
        }
    }
    s[17] = f32x4{-1e30f, -1e30f, -1e30f, -1e30f};
#pragma unroll
    for (int m = 1; m < 16; m <<= 1)
#pragma unroll
        for (int r = 0; r < 4; ++r) mx[r] = fmaxf(mx[r], __shfl_xor(mx[r], m));
    float sum[4] = {0.f, 0.f, 0.f, 0.f};
#pragma unroll
    for (int t = 0; t < 18; ++t)
#pragma unroll
        for (int r = 0; r < 4; ++r) {
            float e = __expf(s[t][r] - mx[r]);
            float ef = b2f(f2b(e));
            s[t][r] = ef;
            sum[r] += ef;
        }
#pragma unroll
    for (int m = 1; m < 16; m <<= 1)
#pragma unroll
        for (int r = 0; r < 4; ++r) sum[r] += __shfl_xor(sum[r], m);
    float inv[4];
#pragma unroll
    for (int r = 0; r < 4; ++r) inv[r] = 1.f / sum[r];

    // PV: 9 k-chunks of 32 over n (fully unrolled, s[] stays in VGPRs)
    f32x4 o[4] = {};
#pragma unroll
    for (int kt = 0; kt < 9; ++kt) {
#pragma unroll
        for (int hh = 0; hh < 2; ++hh) {
            int t = kt * 2 + hh;
#pragma unroll
            for (int r = 0; r < 4; ++r)
                Ps[wave][quad * 4 + r][hh * 16 + cid] = f2b(s[t][r]);
        }
        bf16x8 ap = *(const bf16x8*)&Ps[wave][cid][quad * 8];
#pragma unroll
        for (int dt = 0; dt < 4; ++dt) {
            bf16x8 bv = *(const bf16x8*)(vt + (size_t)(dt * 16 + cid) * NV_ +
                                         kt * 32 + quad * 8);
            o[dt] =
                __builtin_amdgcn_mfma_f32_16x16x32_bf16(ap, bv, o[dt], 0, 0, 0);
        }
    }
#pragma unroll
    for (int dt = 0; dt < 4; ++dt)
#pragma unroll
        for (int r = 0; r < 4; ++r) {
            int row = qt * 16 + quad * 4 + r;
            if (row < N_)
                obuf[(size_t)(b * N_ + row) * 512 + h * 64 + dt * 16 + cid] =
                    f2b(o[dt][r] * inv[r]);
        }
}

// ------- head (fp32, tiny) -------
__global__ void head_k(const float* __restrict__ cls_out,
                       const float* __restrict__ hw,
                       const float* __restrict__ hb, float* __restrict__ out) {
    int t = threadIdx.x;
    if (t >= B_ * NC_) return;
    int b = t / NC_, c = t % NC_;
    float acc = hb[c];
    for (int d = 0; d < D_; ++d) acc += cls_out[b * D_ + d] * hw[d * NC_ + c];
    out[t] = acc;
}

extern "C" void kernel_launch(void* const* d_in, const int* in_sizes, int n_in,
                              void* d_out, int out_size, void* d_ws,
                              size_t ws_size, hipStream_t stream) {
    const float* image     = (const float*)d_in[0];
    const float* ssw       = (const float*)d_in[1];
    const float* ssb       = (const float*)d_in[2];
    const float* ssg       = (const float*)d_in[3];
    const float* ssbeta    = (const float*)d_in[4];
    const float* sow       = (const float*)d_in[5];
    const float* sob       = (const float*)d_in[6];
    const float* sog       = (const float*)d_in[7];
    const float* sobeta    = (const float*)d_in[8];
    const float* fw        = (const float*)d_in[9];
    const float* fb        = (const float*)d_in[10];
    const float* cls_token = (const float*)d_in[11];
    const float* pos_embed = (const float*)d_in[12];
    const float* ln1g      = (const float*)d_in[13];
    const float* ln1b      = (const float*)d_in[14];
    const float* qkvw      = (const float*)d_in[15];
    const float* qkvb      = (const float*)d_in[16];
    const float* projw     = (const float*)d_in[17];
    const float* projb     = (const float*)d_in[18];
    const float* temp      = (const float*)d_in[19];
    const float* ln2g      = (const float*)d_in[20];
    const float* ln2b      = (const float*)d_in[21];
    const float* w1        = (const float*)d_in[22];
    const float* b1        = (const float*)d_in[23];
    const float* w2        = (const float*)d_in[24];
    const float* b2        = (const float*)d_in[25];
    const float* ng        = (const float*)d_in[26];
    const float* nb        = (const float*)d_in[27];
    const float* hw        = (const float*)d_in[28];
    const float* hb        = (const float*)d_in[29];
    float* out = (float*)d_out;

    char* w = (char*)d_ws;
    size_t off = 0;
    float* tokens = (float*)w;                           off += (size_t)MP_ * 512 * 4;
    unsigned short* qkvw_t = (unsigned short*)(w + off); off += (size_t)8 * 1536 * 512 * 2;
    unsigned short* projw_t = (unsigned short*)(w + off); off += (size_t)8 * 512 * 512 * 2;
    unsigned short* w1_t = (unsigned short*)(w + off);   off += (size_t)8 * 2048 * 512 * 2;
    unsigned short* w2_t = (unsigned short*)(w + off);   off += (size_t)8 * 512 * 2048 * 2;
    unsigned short* fw_t = (unsigned short*)(w + off);   off += (size_t)512 * 1024 * 2;
    unsigned short* sswb = (unsigned short*)(w + off);   off += (size_t)512 * 320 * 2;
    unsigned short* sowb = (unsigned short*)(w + off);   off += (size_t)512 * 320 * 2;
    char* S = w + off;

    // prestage aliases (dead after assemble_k)
    unsigned short* Xb   = (unsigned short*)S;
    float* srct          = (float*)(S + 5242880);
    float* origt         = (float*)(S + 5242880 + 16777216);
    unsigned short* comb = (unsigned short*)(S + 5242880 + 2 * 16777216);
    float* gatelin       = (float*)(S + 5242880 + 3 * 16777216);

    // per-layer aliases
    unsigned short* xbuf = (unsigned short*)S;                      // 8,519,680
    unsigned short* qkvB = (unsigned short*)(S + 8519680);          // 25,559,040
    unsigned short* obuf = (unsigned short*)(S + 8519680 + 25559040);            // 8,519,680
    unsigned short* hbuf = (unsigned short*)(S + 8519680 + 25559040 + 8519680);  // 34,078,720
    unsigned short* vt_g = (unsigned short*)(S + 8519680 + 25559040 + 8519680 +
                                             34078720);             // 9,437,184
    float* cls_out = (float*)(S + 8519680 + 25559040 + 8519680 + 34078720 +
                              9437184);

    // ---- weight casts/transposes (bf16, N x K) ----
    castT_k<<<dim3(16, 48, 8), 256, 0, stream>>>(qkvw, qkvw_t, 512, 1536);
    castT_k<<<dim3(16, 16, 8), 256, 0, stream>>>(projw, projw_t, 512, 512);
    castT_k<<<dim3(16, 64, 8), 256, 0, stream>>>(w1, w1_t, 512, 2048);
    castT_k<<<dim3(64, 16, 8), 256, 0, stream>>>(w2, w2_t, 2048, 512);
    castT_k<<<dim3(32, 16, 1), 256, 0, stream>>>(fw, fw_t, 1024, 512);
    cast_k<<<640, 256, 0, stream>>>(ssw, sswb, 512 * 320);
    cast_k<<<640, 256, 0, stream>>>(sow, sowb, 512 * 320);

    // ---- SPT ----
    im2col_k<<<(BP_ * KP_ + 255) / 256, 256, 0, stream>>>(image, Xb);
    dim3 gspt(4, 64);
    gemm_bf16_k<<<gspt, 256, 0, stream>>>(Xb, sswb, ssb, nullptr, srct, nullptr,
                                          512, KP_, EPI_BIAS);
    ln_k<<<BP_, 256, 0, stream>>>(srct, srct, comb, ssg, ssbeta, 512, 512, 1024);
    gemm_bf16_k<<<gspt, 256, 0, stream>>>(Xb, sowb, sob, nullptr, origt, nullptr,
                                          512, KP_, EPI_BIAS);
    ln_k<<<BP_, 256, 0, stream>>>(origt, origt, comb + 512, sog, sobeta, 512,
                                  512, 1024);
    // ---- gated fusion ----
    gemm_bf16_k<<<gspt, 256, 0, stream>>>(comb, fw_t, fb, nullptr, gatelin,
                                          nullptr, 512, 1024, EPI_BIAS);
    assemble_k<<<(B_ * N_ * D_ + 255) / 256, 256, 0, stream>>>(
        gatelin, srct, origt, cls_token, pos_embed, tokens);

    // ---- transformer layers ----
    dim3 gqkv(12, 65), gproj(4, 65), gfc1(16, 65);
    for (int l = 0; l < L_; ++l) {
        const float* l1g = ln1g + l * D_;
        const float* l1b = ln1b + l * D_;
        const unsigned short* qw = qkvw_t + (size_t)l * 1536 * 512;
        const float* qb  = qkvb + (size_t)l * 3 * D_;
        const unsigned short* pw = projw_t + (size_t)l * 512 * 512;
        const float* pb  = projb + (size_t)l * D_;
        const float* tp  = temp + l * H_;
        const float* l2g = ln2g + l * D_;
        const float* l2b = ln2b + l * D_;
        const unsigned short* w1l = w1_t + (size_t)l * 2048 * 512;
        const float* b1l = b1 + (size_t)l * MLP_;
        const unsigned short* w2l = w2_t + (size_t)l * 512 * 2048;
        const float* b2l = b2 + (size_t)l * D_;

        ln_k<<<BN_, 256, 0, stream>>>(tokens, nullptr, xbuf, l1g, l1b, 512, 0,
                                      512);
        gemm_bf16_k<<<gqkv, 256, 0, stream>>>(xbuf, qw, qb, nullptr, nullptr,
                                              qkvB, 1536, 512, EPI_BIAS);
        vT_k<<<dim3(256, 5), 256, 0, stream>>>(qkvB, vt_g);
        attn_fused_k<<<dim3(256, 5), 256, 0, stream>>>(qkvB, vt_g, tp, obuf);
        gemm_bf16_k<<<gproj, 256, 0, stream>>>(obuf, pw, pb, tokens, tokens,
                                               nullptr, 512, 512, EPI_RES);
        ln_k<<<BN_, 256, 0, stream>>>(tokens, nullptr, xbuf, l2g, l2b, 512, 0,
                                      512);
        gemm_bf16_k<<<gfc1, 256, 0, stream>>>(xbuf, w1l, b1l, nullptr, nullptr,
                                              hbuf, 2048, 512, EPI_GELU);
        gemm_bf16_k<<<gproj, 256, 0, stream>>>(hbuf, w2l, b2l, tokens, tokens,
                                               nullptr, 512, 2048, EPI_RES);
    }

    // ---- final LN on cls token + head ----
    ln_k<<<B_, 256, 0, stream>>>(tokens, cls_out, nullptr, ng, nb,
                                 (long)N_ * 512, 512, 0);
    head_k<<<1, 128, 0, stream>>>(cls_out, hw, hb, out);
}